// Round 1
// baseline (98.030 us; speedup 1.0000x reference)
//
#include <hip/hip_runtime.h>

// ApproxConv2d via 256x256 LUT (approximate multiplier).
// out[b,o,y,x] = sum_{c,ky,kx} lut[ qx[b,c,y+ky-1,x+kx-1]*256 + qw[o,c,ky,kx] ] + bias[o]
// qx/qw = clip(rint(v*64), -128, 127) + 128;  out-of-bounds taps hit qx=128 -> lut value 0.
//
// Strategy: one block per (b,o). qw columns for one o span a narrow band
// (weights ~N(0,0.1) -> ~61 distinct columns), so stage a BW=61-column LUT
// band in LDS: band[qx*BW + (col-cmin)]. Column index is lane-uniform per tap,
// row index qx is per-lane -> LDS gather with bank = (29*qx + c)%32 (spread).
// Wave-uniform fallback to global lut for columns outside the band.

#define BW 61          // LUT band width (odd -> good LDS bank spread)
#define NTHREADS 256

__device__ __forceinline__ int quantize(float v) {
    // matches jnp.clip(jnp.round(v*64), -128, 127) + 128  (round half-to-even)
    int q = (int)rintf(v * 64.0f);
    q = q < -128 ? -128 : q;
    q = q > 127 ? 127 : q;
    return q + 128;
}

__global__ __launch_bounds__(NTHREADS, 2)
void approxconv2d_kernel(const float* __restrict__ x,
                         const float* __restrict__ w,
                         const float* __restrict__ bias,
                         const float* __restrict__ lut,
                         float* __restrict__ out)
{
    __shared__ float band[256 * BW];        // 62464 B
    __shared__ unsigned int plane[340];     // 34 rows x 40 byte-cols = 1360 B (halo-padded qx plane)
    __shared__ unsigned char qwrow[576];    // quantized weights for this o
    __shared__ int s_min;

    const int tid = threadIdx.x;
    const int bid = blockIdx.x;
    const int b = bid >> 6;                 // batch
    const int o = bid & 63;                 // output channel

    if (tid == 0) s_min = 255;
    // halo plane: fill everything with 128 (q=0) once; interior rewritten per channel
    for (int i = tid; i < 340; i += NTHREADS) plane[i] = 0x80808080u;
    __syncthreads();

    // quantize this o's 576 weights, track min column
    int lmin = 255;
    for (int i = tid; i < 576; i += NTHREADS) {
        int q = quantize(w[o * 576 + i]);
        qwrow[i] = (unsigned char)q;
        lmin = lmin < q ? lmin : q;
    }
    atomicMin(&s_min, lmin);
    __syncthreads();

    int cmin = s_min;
    if (cmin > 256 - BW) cmin = 256 - BW;   // keep band inside the table

    // stage LUT band: band[qx*BW + cc] = lut[qx*256 + cmin + cc]
    // contiguous i -> conflict-free LDS writes, mostly-coalesced global reads
    for (int i = tid; i < 256 * BW; i += NTHREADS) {
        int qx = i / BW;
        int cc = i - qx * BW;
        band[i] = lut[(qx << 8) + cmin + cc];
    }
    // (covered by the sync at top of the channel loop)

    const int y  = tid >> 3;        // output row 0..31
    const int xq = tid & 7;         // word-column within row
    const int x0 = xq << 2;         // output col base (4 consecutive pixels)

    float acc0 = 0.f, acc1 = 0.f, acc2 = 0.f, acc3 = 0.f;
    const float* xb = x + (size_t)b * 64 * 1024;
    unsigned char* pb = (unsigned char*)plane;

    for (int c = 0; c < 64; ++c) {
        __syncthreads();   // c==0: band/qw ready; c>0: prior channel's reads done

        // stage this channel's quantized 32x32 into plane interior
        float4 xv = *(const float4*)(xb + c * 1024 + y * 32 + x0);
        int qa = quantize(xv.x), qb = quantize(xv.y);
        int qc = quantize(xv.z), qd = quantize(xv.w);
        int wbase = (y + 1) * 40 + x0 + 1;
        pb[wbase + 0] = (unsigned char)qa;
        pb[wbase + 1] = (unsigned char)qb;
        pb[wbase + 2] = (unsigned char)qc;
        pb[wbase + 3] = (unsigned char)qd;
        __syncthreads();

        const unsigned char* qwp = qwrow + c * 9;
        #pragma unroll
        for (int ky = 0; ky < 3; ++ky) {
            int ro = (y + ky) * 10 + xq;            // word index into plane
            unsigned int r0 = plane[ro];
            unsigned int r1 = plane[ro + 1];
            // 6 qx bytes covering taps for 4 pixels
            int ee[6];
            ee[0] = (int)(r0 & 255u);
            ee[1] = (int)((r0 >> 8) & 255u);
            ee[2] = (int)((r0 >> 16) & 255u);
            ee[3] = (int)(r0 >> 24);
            ee[4] = (int)(r1 & 255u);
            ee[5] = (int)((r1 >> 8) & 255u);
            int pp[6];
            #pragma unroll
            for (int t = 0; t < 6; ++t) pp[t] = ee[t] * BW;

            #pragma unroll
            for (int kx = 0; kx < 3; ++kx) {
                int cq = (int)qwp[ky * 3 + kx];     // lane-uniform column
                int cc = cq - cmin;
                if ((unsigned)cc < (unsigned)BW) {  // wave-uniform branch
                    acc0 += band[pp[kx + 0] + cc];
                    acc1 += band[pp[kx + 1] + cc];
                    acc2 += band[pp[kx + 2] + cc];
                    acc3 += band[pp[kx + 3] + cc];
                } else {                             // rare: outside band -> global
                    acc0 += lut[(ee[kx + 0] << 8) + cq];
                    acc1 += lut[(ee[kx + 1] << 8) + cq];
                    acc2 += lut[(ee[kx + 2] << 8) + cq];
                    acc3 += lut[(ee[kx + 3] << 8) + cq];
                }
            }
        }
    }

    float bo = bias[o];
    float4 r;
    r.x = acc0 + bo; r.y = acc1 + bo; r.z = acc2 + bo; r.w = acc3 + bo;
    *(float4*)(out + (size_t)bid * 1024 + y * 32 + x0) = r;
}

extern "C" void kernel_launch(void* const* d_in, const int* in_sizes, int n_in,
                              void* d_out, int out_size, void* d_ws, size_t ws_size,
                              hipStream_t stream) {
    const float* x    = (const float*)d_in[0];
    const float* wgt  = (const float*)d_in[1];
    const float* bias = (const float*)d_in[2];
    const float* lut  = (const float*)d_in[3];
    float* out = (float*)d_out;

    // 512 blocks = 8 batches x 64 output channels; 2 blocks/CU (64.4 KiB LDS each)
    hipLaunchKernelGGL(approxconv2d_kernel, dim3(512), dim3(NTHREADS), 0, stream,
                       x, wgt, bias, lut, out);
}